// Round 1
// baseline (258.416 us; speedup 1.0000x reference)
//
#include <hip/hip_runtime.h>
#include <hip/hip_bf16.h>
#include <math.h>

typedef unsigned long long u64;
typedef unsigned char u8;
typedef unsigned short u16;
typedef unsigned int u32;

#define BB 8
#define CC 19
#define HH 512
#define WW 512
#define HWSZ (HH*WW)
#define NIMG 16

// ---------------------------------------------------------------------------
// 1) fused: argmax over channels -> img_p = (u8)(-cls); img_l = floor(lab*255);
//    zero the loss accumulator.  HBM-bound: must read all 168 MB of inputs.
// ---------------------------------------------------------------------------
__global__ __launch_bounds__(256) void k_pre(const float* __restrict__ pred,
                                             const float* __restrict__ lab,
                                             u8* __restrict__ img,
                                             float* __restrict__ out) {
    int idx = blockIdx.x * 256 + threadIdx.x;   // 4 pixels per thread
    if (idx == 0) out[0] = 0.0f;
    int p4 = idx * 4;
    int b = p4 / HWSZ;
    int rem = p4 - b * HWSZ;
    const float4* base = (const float4*)(pred + (size_t)b * CC * HWSZ + rem);
    float4 best = base[0];
    int ix = 0, iy = 0, iz = 0, iw = 0;
    for (int c = 1; c < CC; ++c) {
        float4 v = base[(size_t)c * (HWSZ / 4)];
        if (v.x > best.x) { best.x = v.x; ix = c; }
        if (v.y > best.y) { best.y = v.y; iy = c; }
        if (v.z > best.z) { best.z = v.z; iz = c; }
        if (v.w > best.w) { best.w = v.w; iw = c; }
    }
    uchar4 o;
    o.x = (u8)(-ix); o.y = (u8)(-iy); o.z = (u8)(-iz); o.w = (u8)(-iw);
    *(uchar4*)(img + p4) = o;
    float4 v = *(const float4*)(lab + p4);
    uchar4 ol;
    ol.x = (u8)(v.x * 255.0f);
    ol.y = (u8)(v.y * 255.0f);
    ol.z = (u8)(v.z * 255.0f);
    ol.w = (u8)(v.w * 255.0f);
    *(uchar4*)(img + (size_t)BB * HWSZ + p4) = ol;
}

// ---------------------------------------------------------------------------
// Sobel for 8 pixels of one row (edge-replicate padding). mag <= 2040.
// ---------------------------------------------------------------------------
__device__ __forceinline__ void sobel8(const u8* __restrict__ base, int yy, int x0,
                                       int mag8[8], u32* dirpack) {
    int r0 = (yy == 0) ? 0 : yy - 1;
    int r2 = (yy == 511) ? 511 : yy + 1;
    const u8* rps[3] = { base + r0 * WW, base + yy * WW, base + r2 * WW };
    int bb[3][10];
#pragma unroll
    for (int r = 0; r < 3; ++r) {
        u64 m = *(const u64*)(rps[r] + x0);
        bb[r][0] = (x0 == 0) ? rps[r][0] : rps[r][x0 - 1];
#pragma unroll
        for (int i = 0; i < 8; ++i) bb[r][i + 1] = (int)((m >> (8 * i)) & 0xFF);
        bb[r][9] = (x0 == 504) ? rps[r][511] : rps[r][x0 + 8];
    }
    u32 dp = 0;
#pragma unroll
    for (int i = 0; i < 8; ++i) {
        int a00 = bb[0][i], a01 = bb[0][i + 1], a02 = bb[0][i + 2];
        int a10 = bb[1][i],                     a12 = bb[1][i + 2];
        int a20 = bb[2][i], a21 = bb[2][i + 1], a22 = bb[2][i + 2];
        int gx = (a02 + 2 * a12 + a22) - (a00 + 2 * a10 + a20);
        int gy = (a20 + 2 * a21 + a22) - (a00 + 2 * a01 + a02);
        int ax = gx < 0 ? -gx : gx;
        int ay = gy < 0 ? -gy : gy;
        mag8[i] = ax + ay;
        if (dirpack) {
            float fax = (float)ax, fay = (float)ay;
            u32 dir;
            if (fay < 0.41421356237309515f * fax) dir = 0;       // <22.5 or >=157.5
            else if (fay >= 2.414213562373095f * fax) dir = 2;   // [67.5,112.5)
            else dir = ((gx ^ gy) >= 0) ? 1u : 3u;               // 45 : 135
            dp |= dir << (2 * i);
        }
    }
    if (dirpack) *dirpack = dp;
}

// ---------------------------------------------------------------------------
// 2) fused Sobel + NMS + double threshold -> bit-packed weak/strong.
// ---------------------------------------------------------------------------
__global__ __launch_bounds__(256) void k_gradnms(const u8* __restrict__ imgs,
                                                 u64* __restrict__ weak,
                                                 u64* __restrict__ strong) {
    __shared__ u16 smag[6][514];         // [row y0-1 .. y0+4][1 + x], cols 0,513 = 0
    __shared__ alignas(8) u8 wb[4][64];
    __shared__ alignas(8) u8 sb[4][64];
    int im = blockIdx.x >> 7;            // 128 strips per image
    int y0 = (blockIdx.x & 127) * 4;
    int r    = threadIdx.x >> 6;         // wave index = row in strip (uniform branches)
    int lane = threadIdx.x & 63;
    int x0 = lane * 8;
    const u8* base = imgs + (size_t)im * HWSZ;

    if (threadIdx.x < 6) { smag[threadIdx.x][0] = 0; smag[threadIdx.x][513] = 0; }

    // pass A: own row mag + dir
    int y = y0 + r;
    int mag8[8]; u32 dp;
    sobel8(base, y, x0, mag8, &dp);
#pragma unroll
    for (int i = 0; i < 8; ++i) smag[r + 1][1 + x0 + i] = (u16)mag8[i];

    // pass B: halo rows (wave-uniform divergence)
    if (r == 0) {
        if (y0 > 0) {
            int m2[8]; sobel8(base, y0 - 1, x0, m2, nullptr);
#pragma unroll
            for (int i = 0; i < 8; ++i) smag[0][1 + x0 + i] = (u16)m2[i];
        } else {
#pragma unroll
            for (int i = 0; i < 8; ++i) smag[0][1 + x0 + i] = 0;
        }
    } else if (r == 3) {
        if (y0 + 4 < 512) {
            int m2[8]; sobel8(base, y0 + 4, x0, m2, nullptr);
#pragma unroll
            for (int i = 0; i < 8; ++i) smag[5][1 + x0 + i] = (u16)m2[i];
        } else {
#pragma unroll
            for (int i = 0; i < 8; ++i) smag[5][1 + x0 + i] = 0;
        }
    }
    __syncthreads();

    // NMS + thresholds
    int wbits = 0, sbits = 0;
#pragma unroll
    for (int i = 0; i < 8; ++i) {
        int x = x0 + i;
        int mag = mag8[i];
        int dir = (int)((dp >> (2 * i)) & 3u);
        int n1, n2;
        switch (dir) {
            case 0:  n1 = smag[r + 1][x];     n2 = smag[r + 1][x + 2]; break;
            case 1:  n1 = smag[r][x + 2];     n2 = smag[r + 2][x];     break;
            case 2:  n1 = smag[r][x + 1];     n2 = smag[r + 2][x + 1]; break;
            default: n1 = smag[r][x];         n2 = smag[r + 2][x + 2]; break;
        }
        int keep = (mag >= n1) & (mag >= n2);
        wbits |= (keep & (mag > 100)) << i;
        sbits |= (keep & (mag > 200)) << i;
    }
    wb[r][lane] = (u8)wbits;
    sb[r][lane] = (u8)sbits;
    __syncthreads();

    if (threadIdx.x < 32) {
        int rr = threadIdx.x >> 3;       // row in strip
        int w  = threadIdx.x & 7;        // u64 word in row
        u64 W = *(const u64*)&wb[rr][w * 8];   // little-endian byte k -> bits 8k
        u64 S = *(const u64*)&sb[rr][w * 8];
        size_t o = ((size_t)im * HH + (y0 + rr)) * 8 + w;
        weak[o] = W;
        strong[o] = S;
    }
}

// ---------------------------------------------------------------------------
// 3) hysteresis to least fixed point.
//    NEW: alternate full horizontal run-fill (row space) with full vertical
//    run-fill (column space) via in-register 512x512 bit-matrix transpose.
//    64x64 intra-tile transpose = 6 shfl_xor stages (wave64 = one tile);
//    tile exchange through conflict-free split-u32 LDS planes. Each pass
//    also does the h-dilate +/-1 hop, which (a) supplies 8-connected
//    diagonal steps and (b) makes a no-change pass in EITHER space a proof
//    that dilate8 is at fixed point (fill covers the row axis, hop covers
//    the other 6 neighbors). Monotone, each pass >= one Jacobi dilate8 step
//    => same fixed point as the (converged) reference.
// ---------------------------------------------------------------------------
__device__ __forceinline__ void tile_transpose64(u64& xr, int lane) {
    u64 x = xr;
#pragma unroll
    for (int k = 0; k < 6; ++k) {
        const int d = 1 << k;
        const u64 m = (k == 0) ? 0x5555555555555555ull :
                      (k == 1) ? 0x3333333333333333ull :
                      (k == 2) ? 0x0F0F0F0F0F0F0F0Full :
                      (k == 3) ? 0x00FF00FF00FF00FFull :
                      (k == 4) ? 0x0000FFFF0000FFFFull :
                                 0x00000000FFFFFFFFull;
        u64 p = (u64)__shfl_xor(x, d, 64);
        // LSB-first convention: swap M[r][c|d] (r&d==0) with M[r|d][c] (c&d==0)
        u64 tl = ((x >> d) ^ p) & m;     // low lane's view
        u64 th = ((p >> d) ^ x) & m;     // high lane's view
        x = (lane & d) ? (x ^ th) : (x ^ (tl << d));
    }
    xr = x;
}

__device__ __forceinline__ void transpose512(u64 v[8], u32 lo[8][512], u32 hi[8][512], int y) {
    int lane = y & 63;
    int w = y >> 6;
#pragma unroll
    for (int j = 0; j < 8; ++j) tile_transpose64(v[j], lane);
    // tile exchange: thread (wave w, lane l) word j -> thread y'=64j+l word w.
    // write to plane[dest word = w], row 64j+l; lane-consecutive -> conflict-free.
#pragma unroll
    for (int j = 0; j < 8; ++j) {
        lo[w][(j << 6) + lane] = (u32)v[j];
        hi[w][(j << 6) + lane] = (u32)(v[j] >> 32);
    }
    __syncthreads();
#pragma unroll
    for (int j = 0; j < 8; ++j) v[j] = (u64)lo[j][y] | ((u64)hi[j][y] << 32);
    __syncthreads();   // protect planes: all reads done before caller rewrites
}

// one pass in the current space: bidirectional run-fill + 8-neighbor hop.
// returns nonzero if anything in the image changed this pass.
__device__ __forceinline__ int hyst_pass(u64 s[8], const u64 W[8],
                                         u32 lo[8][512], u32 hi[8][512],
                                         int* flags, int y, int pc) {
    u64 diff = 0;
    // fill rightward (bit-carry through weak runs)
    u64 c = 0;
#pragma unroll
    for (int j = 0; j < 8; ++j) {
        u64 a = s[j], w = W[j];
        u64 t1 = a + w;       u64 c1 = (u64)(t1 < a);
        u64 t2 = t1 + c;      u64 c2 = (u64)(t2 < t1);
        u64 ns = a | ((t2 ^ w) & w);
        diff |= ns ^ a;
        s[j] = ns;
        c = c1 | c2;
    }
    // fill leftward via bit reversal
    c = 0;
#pragma unroll
    for (int j = 7; j >= 0; --j) {
        u64 a = __builtin_bitreverse64(s[j]);
        u64 w = __builtin_bitreverse64(W[j]);
        u64 t1 = a + w;       u64 c1 = (u64)(t1 < a);
        u64 t2 = t1 + c;      u64 c2 = (u64)(t2 < t1);
        u64 nsr = a | ((t2 ^ w) & w);
        u64 ns = __builtin_bitreverse64(nsr);
        diff |= ns ^ s[j];
        s[j] = ns;
        c = c1 | c2;
    }
    // dilated row -> LDS planes
    u64 hh[8];
#pragma unroll
    for (int j = 0; j < 8; ++j) hh[j] = s[j] | (s[j] << 1) | (s[j] >> 1);
#pragma unroll
    for (int j = 1; j < 8; ++j) hh[j] |= s[j - 1] >> 63;
#pragma unroll
    for (int j = 0; j < 7; ++j) hh[j] |= s[j + 1] << 63;
#pragma unroll
    for (int j = 0; j < 8; ++j) {
        lo[j][y] = (u32)hh[j];
        hi[j][y] = (u32)(hh[j] >> 32);
    }
    if (y == 0) {
        flags[(pc + 1) & 1] = 0;
        if (pc == 0) flags[0] = 0;
    }
    __syncthreads();
    // vertical/diagonal hop (covers all 6 non-row neighbors)
#pragma unroll
    for (int j = 0; j < 8; ++j) {
        u64 up = (y > 0)   ? ((u64)lo[j][y - 1] | ((u64)hi[j][y - 1] << 32)) : 0ull;
        u64 dn = (y < 511) ? ((u64)lo[j][y + 1] | ((u64)hi[j][y + 1] << 32)) : 0ull;
        u64 t = W[j] & (up | dn) & ~s[j];
        diff |= t;
        s[j] |= t;
    }
    if (diff) flags[pc & 1] = 1;
    __syncthreads();
    return flags[pc & 1];
}

__global__ __launch_bounds__(512) void k_hyst(const u64* __restrict__ weakg,
                                              const u64* __restrict__ strongg,
                                              u64* __restrict__ edges) {
    __shared__ u32 hlo[8][512];   // lane stride 4B -> conflict-free
    __shared__ u32 hhi[8][512];
    __shared__ int flags[2];
    int y = threadIdx.x;
    int im = blockIdx.x;
    size_t base = ((size_t)im * HH + y) * 8;
    u64 wk[8], wkT[8], s[8];
#pragma unroll
    for (int j = 0; j < 8; ++j) {
        wk[j] = weakg[base + j];
        s[j] = strongg[base + j];     // strong subset of weak
    }
    // transposed weak mask, computed once
#pragma unroll
    for (int j = 0; j < 8; ++j) wkT[j] = wk[j];
    transpose512(wkT, hlo, hhi, y);

    int pc = 0;
    int inT = 0;
    for (int it = 0; it < 512; ++it) {
        if (!hyst_pass(s, wk, hlo, hhi, flags, y, pc++)) { inT = 0; goto converged; }
        transpose512(s, hlo, hhi, y);
        if (!hyst_pass(s, wkT, hlo, hhi, flags, y, pc++)) { inT = 1; goto converged; }
        transpose512(s, hlo, hhi, y);
    }
    inT = 0;
converged:
    if (inT) transpose512(s, hlo, hhi, y);   // back to row space
#pragma unroll
    for (int j = 0; j < 8; ++j) edges[base + j] = s[j];
}

// ---------------------------------------------------------------------------
// 4) loss. Per column (b,w): k = popcount(ep col), Z = 512 + (e-1)*k,
//    col = elsum*log(Z) - overlap; out = mean over 4096 columns.
// ---------------------------------------------------------------------------
__global__ __launch_bounds__(256) void k_loss(const u64* __restrict__ edges,
                                              float* __restrict__ out) {
    int b = blockIdx.x >> 3;        // image pair index
    int j = blockIdx.x & 7;         // word column
    int wave = threadIdx.x >> 6;
    int lane = threadIdx.x & 63;
    const u64* ep = edges + ((size_t)b * HH) * 8 + j;
    const u64* el = edges + ((size_t)(b + 8) * HH) * 8 + j;
    int k = 0, es = 0, ov = 0;
    int y0 = wave * 128;
    for (int y = y0; y < y0 + 128; ++y) {
        u64 wp = ep[(size_t)y * 8];
        u64 wl = el[(size_t)y * 8];
        int bp = (int)((wp >> lane) & 1ull);
        int bl = (int)((wl >> lane) & 1ull);
        k += bp; es += bl; ov += (bp & bl);
    }
    __shared__ int red[3][4][64];
    red[0][wave][lane] = k;
    red[1][wave][lane] = es;
    red[2][wave][lane] = ov;
    __syncthreads();
    if (threadIdx.x < 64) {
        int l = threadIdx.x;
        int K = red[0][0][l] + red[0][1][l] + red[0][2][l] + red[0][3][l];
        int E = red[1][0][l] + red[1][1][l] + red[1][2][l] + red[1][3][l];
        int O = red[2][0][l] + red[2][1][l] + red[2][2][l] + red[2][3][l];
        float logZ = logf(512.0f + 1.7182818284590452f * (float)K);
        float v = ((float)E * logZ - (float)O) * (1.0f / 4096.0f);
#pragma unroll
        for (int o = 32; o > 0; o >>= 1) v += __shfl_down(v, o, 64);
        if (l == 0) atomicAdd(out, v);
    }
}

// ---------------------------------------------------------------------------
extern "C" void kernel_launch(void* const* d_in, const int* in_sizes, int n_in,
                              void* d_out, int out_size, void* d_ws, size_t ws_size,
                              hipStream_t stream) {
    const float* pred = (const float*)d_in[0];
    const float* labels = (const float*)d_in[1];
    float* out = (float*)d_out;

    // workspace layout (bytes)
    u8*  imgs   = (u8*)d_ws;                                        // 16*HWSZ = 4 MiB
    u64* weak   = (u64*)((char*)d_ws + (size_t)NIMG * HWSZ);        // 512 KiB
    u64* strong = (u64*)((char*)weak + (size_t)NIMG * HH * 8 * 8);  // 512 KiB
    u64* edges  = (u64*)((char*)strong + (size_t)NIMG * HH * 8 * 8);// 512 KiB

    hipLaunchKernelGGL(k_pre, dim3(BB * HWSZ / 4 / 256), dim3(256), 0, stream,
                       pred, labels, imgs, out);
    hipLaunchKernelGGL(k_gradnms, dim3(NIMG * 128), dim3(256), 0, stream,
                       imgs, weak, strong);
    hipLaunchKernelGGL(k_hyst, dim3(NIMG), dim3(512), 0, stream,
                       weak, strong, edges);
    hipLaunchKernelGGL(k_loss, dim3(64), dim3(256), 0, stream, edges, out);
}

// Round 2
// 245.395 us; speedup vs baseline: 1.0531x; 1.0531x over previous
//
#include <hip/hip_runtime.h>
#include <hip/hip_bf16.h>
#include <math.h>

typedef unsigned long long u64;
typedef unsigned char u8;
typedef unsigned short u16;
typedef unsigned int u32;

#define BB 8
#define CC 19
#define HH 512
#define WW 512
#define HWSZ (HH*WW)
#define NIMG 16

// ---------------------------------------------------------------------------
// 1) fused: argmax over channels -> img_p = (u8)(-cls); img_l = floor(lab*255);
//    zero the loss accumulator.  HBM-bound: must read all 168 MB of inputs.
// ---------------------------------------------------------------------------
__global__ __launch_bounds__(256) void k_pre(const float* __restrict__ pred,
                                             const float* __restrict__ lab,
                                             u8* __restrict__ img,
                                             float* __restrict__ out) {
    int idx = blockIdx.x * 256 + threadIdx.x;   // 4 pixels per thread
    if (idx == 0) out[0] = 0.0f;
    int p4 = idx * 4;
    int b = p4 / HWSZ;
    int rem = p4 - b * HWSZ;
    const float4* base = (const float4*)(pred + (size_t)b * CC * HWSZ + rem);
    float4 best = base[0];
    int ix = 0, iy = 0, iz = 0, iw = 0;
    for (int c = 1; c < CC; ++c) {
        float4 v = base[(size_t)c * (HWSZ / 4)];
        if (v.x > best.x) { best.x = v.x; ix = c; }
        if (v.y > best.y) { best.y = v.y; iy = c; }
        if (v.z > best.z) { best.z = v.z; iz = c; }
        if (v.w > best.w) { best.w = v.w; iw = c; }
    }
    uchar4 o;
    o.x = (u8)(-ix); o.y = (u8)(-iy); o.z = (u8)(-iz); o.w = (u8)(-iw);
    *(uchar4*)(img + p4) = o;
    float4 v = *(const float4*)(lab + p4);
    uchar4 ol;
    ol.x = (u8)(v.x * 255.0f);
    ol.y = (u8)(v.y * 255.0f);
    ol.z = (u8)(v.z * 255.0f);
    ol.w = (u8)(v.w * 255.0f);
    *(uchar4*)(img + (size_t)BB * HWSZ + p4) = ol;
}

// ---------------------------------------------------------------------------
// Sobel for 8 pixels of one row (edge-replicate padding). mag <= 2040.
// ---------------------------------------------------------------------------
__device__ __forceinline__ void sobel8(const u8* __restrict__ base, int yy, int x0,
                                       int mag8[8], u32* dirpack) {
    int r0 = (yy == 0) ? 0 : yy - 1;
    int r2 = (yy == 511) ? 511 : yy + 1;
    const u8* rps[3] = { base + r0 * WW, base + yy * WW, base + r2 * WW };
    int bb[3][10];
#pragma unroll
    for (int r = 0; r < 3; ++r) {
        u64 m = *(const u64*)(rps[r] + x0);
        bb[r][0] = (x0 == 0) ? rps[r][0] : rps[r][x0 - 1];
#pragma unroll
        for (int i = 0; i < 8; ++i) bb[r][i + 1] = (int)((m >> (8 * i)) & 0xFF);
        bb[r][9] = (x0 == 504) ? rps[r][511] : rps[r][x0 + 8];
    }
    u32 dp = 0;
#pragma unroll
    for (int i = 0; i < 8; ++i) {
        int a00 = bb[0][i], a01 = bb[0][i + 1], a02 = bb[0][i + 2];
        int a10 = bb[1][i],                     a12 = bb[1][i + 2];
        int a20 = bb[2][i], a21 = bb[2][i + 1], a22 = bb[2][i + 2];
        int gx = (a02 + 2 * a12 + a22) - (a00 + 2 * a10 + a20);
        int gy = (a20 + 2 * a21 + a22) - (a00 + 2 * a01 + a02);
        int ax = gx < 0 ? -gx : gx;
        int ay = gy < 0 ? -gy : gy;
        mag8[i] = ax + ay;
        if (dirpack) {
            float fax = (float)ax, fay = (float)ay;
            u32 dir;
            if (fay < 0.41421356237309515f * fax) dir = 0;       // <22.5 or >=157.5
            else if (fay >= 2.414213562373095f * fax) dir = 2;   // [67.5,112.5)
            else dir = ((gx ^ gy) >= 0) ? 1u : 3u;               // 45 : 135
            dp |= dir << (2 * i);
        }
    }
    if (dirpack) *dirpack = dp;
}

// ---------------------------------------------------------------------------
// 2) fused Sobel + NMS + double threshold -> bit-packed weak/strong.
//    8-row strips: 10 sobel rows per 8 output rows (1.25x redundancy, was
//    1.5x with 4-row strips). Wave w owns rows 2w, 2w+1; waves 0/3 also do
//    the halo rows. Zeroed edge cols emulate the reference's zero-pad of mag.
// ---------------------------------------------------------------------------
__global__ __launch_bounds__(256) void k_gradnms(const u8* __restrict__ imgs,
                                                 u64* __restrict__ weak,
                                                 u64* __restrict__ strong) {
    __shared__ u16 smag[10][514];        // [row y0-1 .. y0+8][1 + x], cols 0,513 = 0
    __shared__ alignas(8) u8 wb[8][64];
    __shared__ alignas(8) u8 sb[8][64];
    int im = blockIdx.x >> 6;            // 64 strips per image
    int y0 = (blockIdx.x & 63) * 8;
    int w    = threadIdx.x >> 6;         // wave index (uniform branches)
    int lane = threadIdx.x & 63;
    int x0 = lane * 8;
    const u8* base = imgs + (size_t)im * HWSZ;

    if (threadIdx.x < 10) { smag[threadIdx.x][0] = 0; smag[threadIdx.x][513] = 0; }

    // pass A: own rows 2w, 2w+1 (mag + dir)
    int ka = 2 * w, kb = 2 * w + 1;      // strip-row indices
    int mag8a[8], mag8b[8]; u32 dpa, dpb;
    sobel8(base, y0 + ka, x0, mag8a, &dpa);
    sobel8(base, y0 + kb, x0, mag8b, &dpb);
#pragma unroll
    for (int i = 0; i < 8; ++i) smag[ka + 1][1 + x0 + i] = (u16)mag8a[i];
#pragma unroll
    for (int i = 0; i < 8; ++i) smag[kb + 1][1 + x0 + i] = (u16)mag8b[i];

    // pass B: halo rows (wave-uniform divergence)
    if (w == 0) {
        if (y0 > 0) {
            int m2[8]; sobel8(base, y0 - 1, x0, m2, nullptr);
#pragma unroll
            for (int i = 0; i < 8; ++i) smag[0][1 + x0 + i] = (u16)m2[i];
        } else {
#pragma unroll
            for (int i = 0; i < 8; ++i) smag[0][1 + x0 + i] = 0;
        }
    } else if (w == 3) {
        if (y0 + 8 < 512) {
            int m2[8]; sobel8(base, y0 + 8, x0, m2, nullptr);
#pragma unroll
            for (int i = 0; i < 8; ++i) smag[9][1 + x0 + i] = (u16)m2[i];
        } else {
#pragma unroll
            for (int i = 0; i < 8; ++i) smag[9][1 + x0 + i] = 0;
        }
    }
    __syncthreads();

    // NMS + thresholds for both owned rows
#pragma unroll
    for (int rr = 0; rr < 2; ++rr) {
        int k = 2 * w + rr;
        const int* m8 = rr ? mag8b : mag8a;
        u32 dp = rr ? dpb : dpa;
        int wbits = 0, sbits = 0;
#pragma unroll
        for (int i = 0; i < 8; ++i) {
            int x = x0 + i;
            int mag = m8[i];
            int dir = (int)((dp >> (2 * i)) & 3u);
            int n1, n2;
            switch (dir) {
                case 0:  n1 = smag[k + 1][x];     n2 = smag[k + 1][x + 2]; break;
                case 1:  n1 = smag[k][x + 2];     n2 = smag[k + 2][x];     break;
                case 2:  n1 = smag[k][x + 1];     n2 = smag[k + 2][x + 1]; break;
                default: n1 = smag[k][x];         n2 = smag[k + 2][x + 2]; break;
            }
            int keep = (mag >= n1) & (mag >= n2);
            wbits |= (keep & (mag > 100)) << i;
            sbits |= (keep & (mag > 200)) << i;
        }
        wb[k][lane] = (u8)wbits;
        sb[k][lane] = (u8)sbits;
    }
    __syncthreads();

    if (threadIdx.x < 64) {
        int rr = threadIdx.x >> 3;       // row in strip
        int wd = threadIdx.x & 7;        // u64 word in row
        u64 W = *(const u64*)&wb[rr][wd * 8];   // little-endian byte k -> bits 8k
        u64 S = *(const u64*)&sb[rr][wd * 8];
        size_t o = ((size_t)im * HH + (y0 + rr)) * 8 + wd;
        weak[o] = W;
        strong[o] = S;
    }
}

// ---------------------------------------------------------------------------
// 3) hysteresis to least fixed point. One block/image, one row (8 u64)/thread.
//    Horizontal run-fill (bit-carry) + vertical Jacobi hop through
//    conflict-free split-u32 LDS. Monotone chaotic iteration => same fixed
//    point as the reference's (converged) 256-cap Jacobi.
// ---------------------------------------------------------------------------
__global__ __launch_bounds__(512) void k_hyst(const u64* __restrict__ weakg,
                                              const u64* __restrict__ strongg,
                                              u64* __restrict__ edges) {
    __shared__ u32 hlo[8][512];   // lane stride 4B -> bank = y%32 -> conflict-free
    __shared__ u32 hhi[8][512];
    __shared__ int flags[2];
    int y = threadIdx.x;
    int im = blockIdx.x;
    size_t base = ((size_t)im * HH + y) * 8;
    u64 wk[8], s[8];
#pragma unroll
    for (int j = 0; j < 8; ++j) {
        wk[j] = weakg[base + j];
        s[j] = strongg[base + j];     // strong subset of weak
    }
    for (int it = 0; it < 256; ++it) {
        u64 diff = 0;
        // horizontal fill rightward
        u64 c = 0;
#pragma unroll
        for (int j = 0; j < 8; ++j) {
            u64 a = s[j], w = wk[j];
            u64 t1 = a + w;       u64 c1 = (u64)(t1 < a);
            u64 t2 = t1 + c;      u64 c2 = (u64)(t2 < t1);
            u64 ns = a | ((t2 ^ w) & w);
            diff |= ns ^ a;
            s[j] = ns;
            c = c1 | c2;
        }
        // horizontal fill leftward via bit reversal
        c = 0;
#pragma unroll
        for (int j = 7; j >= 0; --j) {
            u64 a = __builtin_bitreverse64(s[j]);
            u64 w = __builtin_bitreverse64(wk[j]);
            u64 t1 = a + w;       u64 c1 = (u64)(t1 < a);
            u64 t2 = t1 + c;      u64 c2 = (u64)(t2 < t1);
            u64 nsr = a | ((t2 ^ w) & w);
            u64 ns = __builtin_bitreverse64(nsr);
            diff |= ns ^ s[j];
            s[j] = ns;
            c = c1 | c2;
        }
        // horizontally dilated row -> LDS
        u64 hh[8];
#pragma unroll
        for (int j = 0; j < 8; ++j) hh[j] = s[j] | (s[j] << 1) | (s[j] >> 1);
#pragma unroll
        for (int j = 1; j < 8; ++j) hh[j] |= s[j - 1] >> 63;
#pragma unroll
        for (int j = 0; j < 7; ++j) hh[j] |= s[j + 1] << 63;
#pragma unroll
        for (int j = 0; j < 8; ++j) {
            hlo[j][y] = (u32)hh[j];
            hhi[j][y] = (u32)(hh[j] >> 32);
        }
        if (y == 0 && it == 0) flags[0] = 0;
        __syncthreads();
        if (y == 0) flags[(it + 1) & 1] = 0;
        // vertical/diagonal hop
#pragma unroll
        for (int j = 0; j < 8; ++j) {
            u64 up = (y > 0)   ? ((u64)hlo[j][y - 1] | ((u64)hhi[j][y - 1] << 32)) : 0ull;
            u64 dn = (y < 511) ? ((u64)hlo[j][y + 1] | ((u64)hhi[j][y + 1] << 32)) : 0ull;
            u64 t = wk[j] & (up | dn) & ~s[j];
            diff |= t;
            s[j] |= t;
        }
        if (diff) flags[it & 1] = 1;
        __syncthreads();
        if (!flags[it & 1]) break;
    }
#pragma unroll
    for (int j = 0; j < 8; ++j) edges[base + j] = s[j];
}

// ---------------------------------------------------------------------------
// 64x64 bit-matrix transpose across one wave: 6 shfl_xor stages.
// After the call, lane r's bit c == (input lane c's bit r).
// ---------------------------------------------------------------------------
__device__ __forceinline__ void tile_transpose64(u64& xr, int lane) {
    u64 x = xr;
#pragma unroll
    for (int k = 0; k < 6; ++k) {
        const int d = 1 << k;
        const u64 m = (k == 0) ? 0x5555555555555555ull :
                      (k == 1) ? 0x3333333333333333ull :
                      (k == 2) ? 0x0F0F0F0F0F0F0F0Full :
                      (k == 3) ? 0x00FF00FF00FF00FFull :
                      (k == 4) ? 0x0000FFFF0000FFFFull :
                                 0x00000000FFFFFFFFull;
        u64 p = (u64)__shfl_xor(x, d, 64);
        u64 tl = ((x >> d) ^ p) & m;     // low lane's view
        u64 th = ((p >> d) ^ x) & m;     // high lane's view
        x = (lane & d) ? (x ^ th) : (x ^ (tl << d));
    }
    xr = x;
}

// ---------------------------------------------------------------------------
// 4) loss. Per column (b,x): k = popcount(ep col), Z = 512 + (e-1)*k,
//    col = elsum*log(Z) - overlap; out = mean over 4096 columns.
//    Coalesced row loads + in-wave bit transpose + popcount (replaces the
//    old wave-uniform broadcast loads + per-bit extraction).
// ---------------------------------------------------------------------------
__global__ __launch_bounds__(256) void k_loss(const u64* __restrict__ edges,
                                              float* __restrict__ out) {
    int b = blockIdx.x >> 3;        // image pair index
    int j = blockIdx.x & 7;         // word column (x = 64j + lane)
    int w = threadIdx.x >> 6;
    int lane = threadIdx.x & 63;
    const u64* ep = edges + ((size_t)b * HH) * 8 + j;
    const u64* el = edges + ((size_t)(b + 8) * HH) * 8 + j;
    int k = 0, es = 0, ov = 0;
#pragma unroll
    for (int t = 0; t < 2; ++t) {   // wave w handles row batches 2w, 2w+1
        int yb = (2 * w + t) * 64 + lane;
        u64 vp = ep[(size_t)yb * 8];
        u64 vl = el[(size_t)yb * 8];
        tile_transpose64(vp, lane);   // lane l now holds column 64j+l's 64 row-bits
        tile_transpose64(vl, lane);
        k  += __popcll(vp);
        es += __popcll(vl);
        ov += __popcll(vp & vl);
    }
    __shared__ int red[3][4][64];
    red[0][w][lane] = k;
    red[1][w][lane] = es;
    red[2][w][lane] = ov;
    __syncthreads();
    if (threadIdx.x < 64) {
        int l = threadIdx.x;
        int K = red[0][0][l] + red[0][1][l] + red[0][2][l] + red[0][3][l];
        int E = red[1][0][l] + red[1][1][l] + red[1][2][l] + red[1][3][l];
        int O = red[2][0][l] + red[2][1][l] + red[2][2][l] + red[2][3][l];
        float logZ = logf(512.0f + 1.7182818284590452f * (float)K);
        float v = ((float)E * logZ - (float)O) * (1.0f / 4096.0f);
#pragma unroll
        for (int o = 32; o > 0; o >>= 1) v += __shfl_down(v, o, 64);
        if (l == 0) atomicAdd(out, v);
    }
}

// ---------------------------------------------------------------------------
extern "C" void kernel_launch(void* const* d_in, const int* in_sizes, int n_in,
                              void* d_out, int out_size, void* d_ws, size_t ws_size,
                              hipStream_t stream) {
    const float* pred = (const float*)d_in[0];
    const float* labels = (const float*)d_in[1];
    float* out = (float*)d_out;

    // workspace layout (bytes)
    u8*  imgs   = (u8*)d_ws;                                        // 16*HWSZ = 4 MiB
    u64* weak   = (u64*)((char*)d_ws + (size_t)NIMG * HWSZ);        // 512 KiB
    u64* strong = (u64*)((char*)weak + (size_t)NIMG * HH * 8 * 8);  // 512 KiB
    u64* edges  = (u64*)((char*)strong + (size_t)NIMG * HH * 8 * 8);// 512 KiB

    hipLaunchKernelGGL(k_pre, dim3(BB * HWSZ / 4 / 256), dim3(256), 0, stream,
                       pred, labels, imgs, out);
    hipLaunchKernelGGL(k_gradnms, dim3(NIMG * 64), dim3(256), 0, stream,
                       imgs, weak, strong);
    hipLaunchKernelGGL(k_hyst, dim3(NIMG), dim3(512), 0, stream,
                       weak, strong, edges);
    hipLaunchKernelGGL(k_loss, dim3(64), dim3(256), 0, stream, edges, out);
}

// Round 3
// 234.585 us; speedup vs baseline: 1.1016x; 1.0461x over previous
//
#include <hip/hip_runtime.h>
#include <hip/hip_bf16.h>
#include <math.h>

typedef unsigned long long u64;
typedef unsigned char u8;
typedef unsigned short u16;
typedef unsigned int u32;
typedef float f32x4 __attribute__((ext_vector_type(4)));

#define BB 8
#define CC 19
#define HH 512
#define WW 512
#define HWSZ (HH*WW)
#define NIMG 16

// ---------------------------------------------------------------------------
// 1) fused: argmax over channels -> img_p = (u8)(-cls); img_l = floor(lab*255);
//    zero the loss accumulator.  HBM-bound: must read all 168 MB of inputs.
//    Nontemporal loads: pred/labels are zero-reuse streams >> L2+L3.
// ---------------------------------------------------------------------------
__global__ __launch_bounds__(256) void k_pre(const float* __restrict__ pred,
                                             const float* __restrict__ lab,
                                             u8* __restrict__ img,
                                             float* __restrict__ out) {
    int idx = blockIdx.x * 256 + threadIdx.x;   // 4 pixels per thread
    if (idx == 0) out[0] = 0.0f;
    int p4 = idx * 4;
    int b = p4 / HWSZ;
    int rem = p4 - b * HWSZ;
    const f32x4* base = (const f32x4*)(pred + (size_t)b * CC * HWSZ + rem);
    f32x4 best = __builtin_nontemporal_load(&base[0]);
    int ix = 0, iy = 0, iz = 0, iw = 0;
    for (int c = 1; c < CC; ++c) {
        f32x4 v = __builtin_nontemporal_load(&base[(size_t)c * (HWSZ / 4)]);
        if (v.x > best.x) { best.x = v.x; ix = c; }
        if (v.y > best.y) { best.y = v.y; iy = c; }
        if (v.z > best.z) { best.z = v.z; iz = c; }
        if (v.w > best.w) { best.w = v.w; iw = c; }
    }
    uchar4 o;
    o.x = (u8)(-ix); o.y = (u8)(-iy); o.z = (u8)(-iz); o.w = (u8)(-iw);
    *(uchar4*)(img + p4) = o;
    f32x4 v = __builtin_nontemporal_load((const f32x4*)(lab + p4));
    uchar4 ol;
    ol.x = (u8)(v.x * 255.0f);
    ol.y = (u8)(v.y * 255.0f);
    ol.z = (u8)(v.z * 255.0f);
    ol.w = (u8)(v.w * 255.0f);
    *(uchar4*)(img + (size_t)BB * HWSZ + p4) = ol;
}

// ---------------------------------------------------------------------------
// Sobel for 8 pixels of one row (edge-replicate padding). mag <= 2040.
// ---------------------------------------------------------------------------
__device__ __forceinline__ void sobel8(const u8* __restrict__ base, int yy, int x0,
                                       int mag8[8], u32* dirpack) {
    int r0 = (yy == 0) ? 0 : yy - 1;
    int r2 = (yy == 511) ? 511 : yy + 1;
    const u8* rps[3] = { base + r0 * WW, base + yy * WW, base + r2 * WW };
    int bb[3][10];
#pragma unroll
    for (int r = 0; r < 3; ++r) {
        u64 m = *(const u64*)(rps[r] + x0);
        bb[r][0] = (x0 == 0) ? rps[r][0] : rps[r][x0 - 1];
#pragma unroll
        for (int i = 0; i < 8; ++i) bb[r][i + 1] = (int)((m >> (8 * i)) & 0xFF);
        bb[r][9] = (x0 == 504) ? rps[r][511] : rps[r][x0 + 8];
    }
    u32 dp = 0;
#pragma unroll
    for (int i = 0; i < 8; ++i) {
        int a00 = bb[0][i], a01 = bb[0][i + 1], a02 = bb[0][i + 2];
        int a10 = bb[1][i],                     a12 = bb[1][i + 2];
        int a20 = bb[2][i], a21 = bb[2][i + 1], a22 = bb[2][i + 2];
        int gx = (a02 + 2 * a12 + a22) - (a00 + 2 * a10 + a20);
        int gy = (a20 + 2 * a21 + a22) - (a00 + 2 * a01 + a02);
        int ax = gx < 0 ? -gx : gx;
        int ay = gy < 0 ? -gy : gy;
        mag8[i] = ax + ay;
        if (dirpack) {
            float fax = (float)ax, fay = (float)ay;
            u32 dir;
            if (fay < 0.41421356237309515f * fax) dir = 0;       // <22.5 or >=157.5
            else if (fay >= 2.414213562373095f * fax) dir = 2;   // [67.5,112.5)
            else dir = ((gx ^ gy) >= 0) ? 1u : 3u;               // 45 : 135
            dp |= dir << (2 * i);
        }
    }
    if (dirpack) *dirpack = dp;
}

// ---------------------------------------------------------------------------
// 2) fused Sobel + NMS + double threshold -> bit-packed weak/strong.
//    8-row strips: 10 sobel rows per 8 output rows (1.25x redundancy).
// ---------------------------------------------------------------------------
__global__ __launch_bounds__(256) void k_gradnms(const u8* __restrict__ imgs,
                                                 u64* __restrict__ weak,
                                                 u64* __restrict__ strong) {
    __shared__ u16 smag[10][514];        // [row y0-1 .. y0+8][1 + x], cols 0,513 = 0
    __shared__ alignas(8) u8 wb[8][64];
    __shared__ alignas(8) u8 sb[8][64];
    int im = blockIdx.x >> 6;            // 64 strips per image
    int y0 = (blockIdx.x & 63) * 8;
    int w    = threadIdx.x >> 6;         // wave index (uniform branches)
    int lane = threadIdx.x & 63;
    int x0 = lane * 8;
    const u8* base = imgs + (size_t)im * HWSZ;

    if (threadIdx.x < 10) { smag[threadIdx.x][0] = 0; smag[threadIdx.x][513] = 0; }

    // pass A: own rows 2w, 2w+1 (mag + dir)
    int ka = 2 * w, kb = 2 * w + 1;      // strip-row indices
    int mag8a[8], mag8b[8]; u32 dpa, dpb;
    sobel8(base, y0 + ka, x0, mag8a, &dpa);
    sobel8(base, y0 + kb, x0, mag8b, &dpb);
#pragma unroll
    for (int i = 0; i < 8; ++i) smag[ka + 1][1 + x0 + i] = (u16)mag8a[i];
#pragma unroll
    for (int i = 0; i < 8; ++i) smag[kb + 1][1 + x0 + i] = (u16)mag8b[i];

    // pass B: halo rows (wave-uniform divergence)
    if (w == 0) {
        if (y0 > 0) {
            int m2[8]; sobel8(base, y0 - 1, x0, m2, nullptr);
#pragma unroll
            for (int i = 0; i < 8; ++i) smag[0][1 + x0 + i] = (u16)m2[i];
        } else {
#pragma unroll
            for (int i = 0; i < 8; ++i) smag[0][1 + x0 + i] = 0;
        }
    } else if (w == 3) {
        if (y0 + 8 < 512) {
            int m2[8]; sobel8(base, y0 + 8, x0, m2, nullptr);
#pragma unroll
            for (int i = 0; i < 8; ++i) smag[9][1 + x0 + i] = (u16)m2[i];
        } else {
#pragma unroll
            for (int i = 0; i < 8; ++i) smag[9][1 + x0 + i] = 0;
        }
    }
    __syncthreads();

    // NMS + thresholds for both owned rows
#pragma unroll
    for (int rr = 0; rr < 2; ++rr) {
        int k = 2 * w + rr;
        const int* m8 = rr ? mag8b : mag8a;
        u32 dp = rr ? dpb : dpa;
        int wbits = 0, sbits = 0;
#pragma unroll
        for (int i = 0; i < 8; ++i) {
            int x = x0 + i;
            int mag = m8[i];
            int dir = (int)((dp >> (2 * i)) & 3u);
            int n1, n2;
            switch (dir) {
                case 0:  n1 = smag[k + 1][x];     n2 = smag[k + 1][x + 2]; break;
                case 1:  n1 = smag[k][x + 2];     n2 = smag[k + 2][x];     break;
                case 2:  n1 = smag[k][x + 1];     n2 = smag[k + 2][x + 1]; break;
                default: n1 = smag[k][x];         n2 = smag[k + 2][x + 2]; break;
            }
            int keep = (mag >= n1) & (mag >= n2);
            wbits |= (keep & (mag > 100)) << i;
            sbits |= (keep & (mag > 200)) << i;
        }
        wb[k][lane] = (u8)wbits;
        sb[k][lane] = (u8)sbits;
    }
    __syncthreads();

    if (threadIdx.x < 64) {
        int rr = threadIdx.x >> 3;       // row in strip
        int wd = threadIdx.x & 7;        // u64 word in row
        u64 W = *(const u64*)&wb[rr][wd * 8];   // little-endian byte k -> bits 8k
        u64 S = *(const u64*)&sb[rr][wd * 8];
        size_t o = ((size_t)im * HH + (y0 + rr)) * 8 + wd;
        weak[o] = W;
        strong[o] = S;
    }
}

// ---------------------------------------------------------------------------
// 3) hysteresis to least fixed point. One block/image, one row (8 u64)/thread.
//    Full pass = bidirectional horizontal run-fill + vertical/diag hop.
//    Between full passes: up to 3 CHEAP vertical hops (~1/4 cost) that skip
//    the run-fill -- after the first iterations the horizontal fill is
//    saturated and only vertical seepage remains. Termination is declared
//    only on a zero-diff FULL pass (fill covers the row axis, hop covers the
//    other 6 neighbors => genuine dilate8 fixed point). All updates are
//    monotone and LDS words are 4B-atomic, so the post-hop refresh written
//    concurrently with neighbor reads is a benign (old-or-new) race.
// ---------------------------------------------------------------------------
__device__ __forceinline__ void hdilate(const u64 s[8], u64 hh[8]) {
#pragma unroll
    for (int j = 0; j < 8; ++j) hh[j] = s[j] | (s[j] << 1) | (s[j] >> 1);
#pragma unroll
    for (int j = 1; j < 8; ++j) hh[j] |= s[j - 1] >> 63;
#pragma unroll
    for (int j = 0; j < 7; ++j) hh[j] |= s[j + 1] << 63;
}

__device__ __forceinline__ int full_pass(u64 s[8], const u64 wk[8],
                                         u32 lo[8][512], u32 hi[8][512],
                                         int* flags, int y, int pc) {
    u64 diff = 0;
    // horizontal fill rightward (bit-carry through weak runs)
    u64 c = 0;
#pragma unroll
    for (int j = 0; j < 8; ++j) {
        u64 a = s[j], w = wk[j];
        u64 t1 = a + w;       u64 c1 = (u64)(t1 < a);
        u64 t2 = t1 + c;      u64 c2 = (u64)(t2 < t1);
        u64 ns = a | ((t2 ^ w) & w);
        diff |= ns ^ a;
        s[j] = ns;
        c = c1 | c2;
    }
    // horizontal fill leftward via bit reversal
    c = 0;
#pragma unroll
    for (int j = 7; j >= 0; --j) {
        u64 a = __builtin_bitreverse64(s[j]);
        u64 w = __builtin_bitreverse64(wk[j]);
        u64 t1 = a + w;       u64 c1 = (u64)(t1 < a);
        u64 t2 = t1 + c;      u64 c2 = (u64)(t2 < t1);
        u64 nsr = a | ((t2 ^ w) & w);
        u64 ns = __builtin_bitreverse64(nsr);
        diff |= ns ^ s[j];
        s[j] = ns;
        c = c1 | c2;
    }
    // h-dilated row -> LDS
    u64 hh[8];
    hdilate(s, hh);
#pragma unroll
    for (int j = 0; j < 8; ++j) { lo[j][y] = (u32)hh[j]; hi[j][y] = (u32)(hh[j] >> 32); }
    __syncthreads();
    if (y == 0) flags[(pc + 1) & 1] = 0;
    // vertical/diagonal hop
    u64 hdiff = 0;
#pragma unroll
    for (int j = 0; j < 8; ++j) {
        u64 up = (y > 0)   ? ((u64)lo[j][y - 1] | ((u64)hi[j][y - 1] << 32)) : 0ull;
        u64 dn = (y < 511) ? ((u64)lo[j][y + 1] | ((u64)hi[j][y + 1] << 32)) : 0ull;
        u64 t = wk[j] & (up | dn) & ~s[j];
        hdiff |= t;
        s[j] |= t;
    }
    diff |= hdiff;
    if (hdiff) {   // refresh so following vhops see post-hop state (benign race)
        hdilate(s, hh);
#pragma unroll
        for (int j = 0; j < 8; ++j) { lo[j][y] = (u32)hh[j]; hi[j][y] = (u32)(hh[j] >> 32); }
    }
    if (diff) flags[pc & 1] = 1;
    __syncthreads();
    return flags[pc & 1];
}

__device__ __forceinline__ int vhop(u64 s[8], const u64 wk[8],
                                    u32 lo[8][512], u32 hi[8][512],
                                    int* flags, int y, int pc) {
    u64 t[8]; u64 diff = 0;
#pragma unroll
    for (int j = 0; j < 8; ++j) {
        u64 up = (y > 0)   ? ((u64)lo[j][y - 1] | ((u64)hi[j][y - 1] << 32)) : 0ull;
        u64 dn = (y < 511) ? ((u64)lo[j][y + 1] | ((u64)hi[j][y + 1] << 32)) : 0ull;
        t[j] = wk[j] & (up | dn) & ~s[j];
        diff |= t[j];
    }
    __syncthreads();                 // all reads done before any rewrite
    if (y == 0) flags[(pc + 1) & 1] = 0;
    if (diff) {
        flags[pc & 1] = 1;
#pragma unroll
        for (int j = 0; j < 8; ++j) s[j] |= t[j];
        u64 hh[8];
        hdilate(s, hh);
#pragma unroll
        for (int j = 0; j < 8; ++j) { lo[j][y] = (u32)hh[j]; hi[j][y] = (u32)(hh[j] >> 32); }
    }
    __syncthreads();
    return flags[pc & 1];
}

__global__ __launch_bounds__(512) void k_hyst(const u64* __restrict__ weakg,
                                              const u64* __restrict__ strongg,
                                              u64* __restrict__ edges) {
    __shared__ u32 hlo[8][512];   // lane stride 4B -> bank = y%32 -> conflict-free
    __shared__ u32 hhi[8][512];
    __shared__ int flags[2];
    int y = threadIdx.x;
    int im = blockIdx.x;
    size_t base = ((size_t)im * HH + y) * 8;
    u64 wk[8], s[8];
#pragma unroll
    for (int j = 0; j < 8; ++j) {
        wk[j] = weakg[base + j];
        s[j] = strongg[base + j];     // strong subset of weak
    }
    if (y == 0) flags[0] = 0;         // first set happens after full_pass's sync1
    int pc = 0;
    for (int it = 0; it < 256; ++it) {
        if (!full_pass(s, wk, hlo, hhi, flags, y, pc++)) break;
#pragma unroll 1
        for (int v = 0; v < 3; ++v)
            if (!vhop(s, wk, hlo, hhi, flags, y, pc++)) break;
    }
#pragma unroll
    for (int j = 0; j < 8; ++j) edges[base + j] = s[j];
}

// ---------------------------------------------------------------------------
// 64x64 bit-matrix transpose across one wave: 6 shfl_xor stages.
// ---------------------------------------------------------------------------
__device__ __forceinline__ void tile_transpose64(u64& xr, int lane) {
    u64 x = xr;
#pragma unroll
    for (int k = 0; k < 6; ++k) {
        const int d = 1 << k;
        const u64 m = (k == 0) ? 0x5555555555555555ull :
                      (k == 1) ? 0x3333333333333333ull :
                      (k == 2) ? 0x0F0F0F0F0F0F0F0Full :
                      (k == 3) ? 0x00FF00FF00FF00FFull :
                      (k == 4) ? 0x0000FFFF0000FFFFull :
                                 0x00000000FFFFFFFFull;
        u64 p = (u64)__shfl_xor(x, d, 64);
        u64 tl = ((x >> d) ^ p) & m;     // low lane's view
        u64 th = ((p >> d) ^ x) & m;     // high lane's view
        x = (lane & d) ? (x ^ th) : (x ^ (tl << d));
    }
    xr = x;
}

// ---------------------------------------------------------------------------
// 4) loss. Per column (b,x): k = popcount(ep col), Z = 512 + (e-1)*k,
//    col = elsum*log(Z) - overlap; out = mean over 4096 columns.
//    Coalesced row loads + in-wave bit transpose + popcount.
// ---------------------------------------------------------------------------
__global__ __launch_bounds__(256) void k_loss(const u64* __restrict__ edges,
                                              float* __restrict__ out) {
    int b = blockIdx.x >> 3;        // image pair index
    int j = blockIdx.x & 7;         // word column (x = 64j + lane)
    int w = threadIdx.x >> 6;
    int lane = threadIdx.x & 63;
    const u64* ep = edges + ((size_t)b * HH) * 8 + j;
    const u64* el = edges + ((size_t)(b + 8) * HH) * 8 + j;
    int k = 0, es = 0, ov = 0;
#pragma unroll
    for (int t = 0; t < 2; ++t) {   // wave w handles row batches 2w, 2w+1
        int yb = (2 * w + t) * 64 + lane;
        u64 vp = ep[(size_t)yb * 8];
        u64 vl = el[(size_t)yb * 8];
        tile_transpose64(vp, lane);   // lane l now holds column 64j+l's 64 row-bits
        tile_transpose64(vl, lane);
        k  += __popcll(vp);
        es += __popcll(vl);
        ov += __popcll(vp & vl);
    }
    __shared__ int red[3][4][64];
    red[0][w][lane] = k;
    red[1][w][lane] = es;
    red[2][w][lane] = ov;
    __syncthreads();
    if (threadIdx.x < 64) {
        int l = threadIdx.x;
        int K = red[0][0][l] + red[0][1][l] + red[0][2][l] + red[0][3][l];
        int E = red[1][0][l] + red[1][1][l] + red[1][2][l] + red[1][3][l];
        int O = red[2][0][l] + red[2][1][l] + red[2][2][l] + red[2][3][l];
        float logZ = logf(512.0f + 1.7182818284590452f * (float)K);
        float v = ((float)E * logZ - (float)O) * (1.0f / 4096.0f);
#pragma unroll
        for (int o = 32; o > 0; o >>= 1) v += __shfl_down(v, o, 64);
        if (l == 0) atomicAdd(out, v);
    }
}

// ---------------------------------------------------------------------------
extern "C" void kernel_launch(void* const* d_in, const int* in_sizes, int n_in,
                              void* d_out, int out_size, void* d_ws, size_t ws_size,
                              hipStream_t stream) {
    const float* pred = (const float*)d_in[0];
    const float* labels = (const float*)d_in[1];
    float* out = (float*)d_out;

    // workspace layout (bytes)
    u8*  imgs   = (u8*)d_ws;                                        // 16*HWSZ = 4 MiB
    u64* weak   = (u64*)((char*)d_ws + (size_t)NIMG * HWSZ);        // 512 KiB
    u64* strong = (u64*)((char*)weak + (size_t)NIMG * HH * 8 * 8);  // 512 KiB
    u64* edges  = (u64*)((char*)strong + (size_t)NIMG * HH * 8 * 8);// 512 KiB

    hipLaunchKernelGGL(k_pre, dim3(BB * HWSZ / 4 / 256), dim3(256), 0, stream,
                       pred, labels, imgs, out);
    hipLaunchKernelGGL(k_gradnms, dim3(NIMG * 64), dim3(256), 0, stream,
                       imgs, weak, strong);
    hipLaunchKernelGGL(k_hyst, dim3(NIMG), dim3(512), 0, stream,
                       weak, strong, edges);
    hipLaunchKernelGGL(k_loss, dim3(64), dim3(256), 0, stream, edges, out);
}